// Round 14
// baseline (111.920 us; speedup 1.0000x reference)
//
#include <hip/hip_runtime.h>
#include <hip/hip_bf16.h>

#define BT      8192
#define DIN     2048
#define DOUT    2048
#define NEXP    8
#define RANK    8
#define KX      2112         /* DIN + NEXP*RANK */
#define NSUB    66           /* KX / 32 */
#define NSPLIT  4            /* K-split for the h-GEMM */
#define HLD     72           /* HP leading dim: cols 0-7 logits, 8-71 h */
#define SCALING 1.0f         /* ALPHA / RANK = 8/8 */
#define SLOTSZ  24576        /* A 128x32 (8KB) + B 256x32 (16KB) */
#define LDSZ    73728        /* ring-3 */

typedef __bf16 bf16x8 __attribute__((ext_vector_type(8)));
typedef __bf16 bf16x4 __attribute__((ext_vector_type(4)));
typedef float  f32x4  __attribute__((ext_vector_type(4)));

/* ---- ws layout (bytes) ---- */
#define XB_OFF     0
#define XB_BYTES   (BT * KX * 2)
#define WB_OFF     (XB_OFF + XB_BYTES)
#define WB_BYTES   (DOUT * KX * 2)
#define ACAT_OFF   (WB_OFF + WB_BYTES)
#define ACAT_BYTES (128 * DIN * 2)
#define HP_OFF     (ACAT_OFF + ACAT_BYTES)
#define HP_BYTES   (NSPLIT * BT * HLD * 4)

__device__ __forceinline__ void gload_lds16(const void* g, void* l) {
    __builtin_amdgcn_global_load_lds(
        (__attribute__((address_space(1))) void*)(g),
        (__attribute__((address_space(3))) void*)(l),
        16, 0, 0);
}

#define MFMA16(a, b, c) __builtin_amdgcn_mfma_f32_16x16x32_bf16((a), (b), (c), 0, 0, 0)

/* ---------------- prep: weights -> bf16 staged layouts ---------------- */
__global__ __launch_bounds__(256) void mole_prep(
    const float* __restrict__ Wf, const float* __restrict__ Bm,
    const float* __restrict__ Wr, const float* __restrict__ A,
    __bf16* __restrict__ WB, __bf16* __restrict__ ACAT)
{
    const int i = blockIdx.x * 256 + threadIdx.x;
    const int R1 = DOUT * (DIN / 4);
    const int R2 = DOUT * 64;
    if (i < R1) {
        const int o = i >> 9, c4 = i & 511;
        float4 v = ((const float4*)Wf)[(size_t)o * 512 + c4];
        bf16x4 b; b[0] = (__bf16)v.x; b[1] = (__bf16)v.y; b[2] = (__bf16)v.z; b[3] = (__bf16)v.w;
        *(bf16x4*)&WB[(size_t)o * KX + (c4 << 2)] = b;
    } else if (i < R1 + R2) {
        const int j = i - R1;
        const int o = j >> 6, c = j & 63;
        const int e = c >> 3, r = c & 7;
        WB[(size_t)o * KX + DIN + c] = (__bf16)Bm[((size_t)e * DOUT + o) * RANK + r];
    } else {
        const int j = i - (R1 + R2);
        const int r = j >> 9, c4 = j & 511;
        float4 v;
        if (r < 8)        v = ((const float4*)Wr)[(size_t)r * 512 + c4];
        else if (r < 72)  v = ((const float4*)A)[(size_t)(r - 8) * 512 + c4];
        else              v = make_float4(0.f, 0.f, 0.f, 0.f);
        bf16x4 b; b[0] = (__bf16)v.x; b[1] = (__bf16)v.y; b[2] = (__bf16)v.z; b[3] = (__bf16)v.w;
        *(bf16x4*)&ACAT[(size_t)r * DIN + (c4 << 2)] = b;
    }
}

/* ==== fused h-GEMM: x(fp32)->bf16 convert + XB side-write + MFMA vs ACAT ==== */
__global__ __launch_bounds__(256) void mole_hconv(
    const float* __restrict__ x, const __bf16* __restrict__ ACAT,
    __bf16* __restrict__ XB, float* __restrict__ HP)
{
    __shared__ __align__(16) __bf16 Xs[128][32];
    __shared__ __align__(16) __bf16 Bs[128][32];

    const int tid = threadIdx.x;
    const int wv  = tid >> 6, ln = tid & 63;
    const int wr  = wv >> 1, wc = wv & 1;
    const size_t m0 = (size_t)blockIdx.x * 128;
    const int kStart = blockIdx.z * (DIN / NSPLIT);
    float* C = HP + (size_t)blockIdx.z * BT * HLD;

    const int xr = tid >> 3;
    const int xc = (tid & 7) << 2;
    const float* gx  = x  + (m0 + xr) * (size_t)DIN + kStart + xc;
    __bf16*      gxb = XB + (m0 + xr) * (size_t)KX  + kStart + xc;

    const int srow = (wv << 4) + (ln >> 2);
    const int scol = (ln & 3) << 3;
    const __bf16* gB0 = ACAT + srow * (size_t)DIN + kStart + scol;
    const __bf16* gB1 = gB0 + (size_t)64 * DIN;
    __bf16* lB0 = &Bs[(wv << 4)][0];
    __bf16* lB1 = &Bs[64 + (wv << 4)][0];

    f32x4 acc[4][4] = {};
    const int fr = ln & 15;
    const int fk = (ln >> 4) << 3;

    for (int ks = 0; ks < (DIN / NSPLIT) / 32; ++ks) {
        gload_lds16(gB0, lB0);
        gload_lds16(gB1, lB1);
        gB0 += 32; gB1 += 32;
        #pragma unroll
        for (int j = 0; j < 4; ++j) {
            float4 v = *(const float4*)(gx + (size_t)(32 * j) * DIN + 32 * ks);
            bf16x4 b; b[0] = (__bf16)v.x; b[1] = (__bf16)v.y;
            b[2] = (__bf16)v.z; b[3] = (__bf16)v.w;
            *(bf16x4*)&Xs[xr + 32 * j][xc] = b;
            *(bf16x4*)(gxb + (size_t)(32 * j) * KX + 32 * ks) = b;
        }
        __syncthreads();

        bf16x8 af[4], bfr[4];
        #pragma unroll
        for (int m = 0; m < 4; ++m)
            af[m] = *(const bf16x8*)&Xs[(wr << 6) + (m << 4) + fr][fk];
        #pragma unroll
        for (int n = 0; n < 4; ++n)
            bfr[n] = *(const bf16x8*)&Bs[(wc << 6) + (n << 4) + fr][fk];
        #pragma unroll
        for (int m = 0; m < 4; ++m)
            #pragma unroll
            for (int n = 0; n < 4; ++n)
                acc[m][n] = MFMA16(af[m], bfr[n], acc[m][n]);
        __syncthreads();
    }

    const int cr = (ln >> 4) << 2;
    const int cc = ln & 15;
    #pragma unroll
    for (int n = 0; n < 4; ++n) {
        const int col = (wc << 6) + (n << 4) + cc;
        if (col < HLD) {
            #pragma unroll
            for (int m = 0; m < 4; ++m) {
                const size_t row = m0 + (wr << 6) + (m << 4) + cr;
                #pragma unroll
                for (int r = 0; r < 4; ++r)
                    C[(row + r) * (size_t)HLD + col] = acc[m][n][r];
            }
        }
    }
}

/* --------- per-token: logits (HP cols 0-7 + br) -> softmax -> w; g -> XB --- */
__global__ __launch_bounds__(256) void mole_softmax_g(
    const float* __restrict__ HP, const float* __restrict__ br,
    float* __restrict__ wOut, __bf16* __restrict__ XB)
{
    const int t   = blockIdx.x * 4 + (threadIdx.x >> 6);
    const int tid = threadIdx.x & 63;
    float h = 0.0f;
    #pragma unroll
    for (int sp = 0; sp < NSPLIT; ++sp)
        h += HP[((size_t)sp * BT + t) * HLD + 8 + tid];

    float lg[NEXP];
    #pragma unroll
    for (int e = 0; e < NEXP; ++e) {
        lg[e] = br[e];
        #pragma unroll
        for (int sp = 0; sp < NSPLIT; ++sp)
            lg[e] += HP[((size_t)sp * BT + t) * HLD + e];
    }
    float mx = lg[0];
    #pragma unroll
    for (int e = 1; e < NEXP; ++e) mx = fmaxf(mx, lg[e]);
    float ex[NEXP], den = 0.0f;
    #pragma unroll
    for (int e = 0; e < NEXP; ++e) { ex[e] = expf(lg[e] - mx); den += ex[e]; }

    const float w_my = ex[tid >> 3] / den;
    XB[(size_t)t * KX + DIN + tid] = (__bf16)(SCALING * w_my * h);
    if (tid < NEXP) wOut[(size_t)t * NEXP + tid] = ex[tid] / den;
}

/* ==== main GEMM: 128x256 tile, ring-3 BK=32, 2 blocks/CU (cross-block TLP)
   C[8192,2048] = XB * WB^T + bias. Grid 512 = 2 blocks/CU: barrier-
   independent blocks interleave (one reads LDS while the other MFMAs) --
   the overlap all intra-block schedules failed to create (R4-R11, m114
   mechanism). 8 waves (2M x 4N), per-wave 64x64, acc 4x4 f32x4 (64 VGPR).
   LDS: 3 ring slots x [A 128x32 | B 256x32] = 72 KB; x2 blocks = 144 KB.
   Swizzle phys16B = k ^ ((row>>1)&3) (0-conflict, verified R4); staged
   via pre-swizzled global source, linear LDS dest.
   Step s: vmcnt(3) [chunk s landed; s+1 in flight] -> barrier -> 8
   ds_read -> stage chunk s+2 (3 loads/thread) -> 16 MFMA.
   Invariant at entry: {s, s+1} outstanding (6 loads). WAR: slot (s+2)%3
   was read at step s-1, fenced by this barrier. Tail vmcnt 3/0. */
__global__ __launch_bounds__(512, 4) void mole_gemm128x256(
    const __bf16* __restrict__ XBp, const __bf16* __restrict__ WBp,
    float* __restrict__ C, const float* __restrict__ bias)
{
    __shared__ __align__(16) char smem[LDSZ];

    const int tid = threadIdx.x;
    const int wv  = tid >> 6, l = tid & 63;
    const int wm  = wv >> 2, wn = wv & 3;
    const int bid = blockIdx.x;
    /* T1: XCD x owns tm in [8x, 8x+8) x all tn -> A panel 4.3 MB L2-fit */
    const int xcd = bid & 7, ib = bid >> 3;
    const int tm = xcd * 8 + (ib & 7), tn = ib >> 3;
    const size_t m0 = (size_t)tm * 128, n0 = (size_t)tn * 256;

    /* staging (3 instrs/wave/chunk): A rows [16wv,16wv+16);
       B rows [32wv,32wv+32). lane l -> row +(l>>2), phys slot l&3,
       logical col ((l&3)^((l>>3)&3))*8  (inverse of read swizzle) */
    const int swcol = ((l & 3) ^ ((l >> 3) & 3)) << 3;
    const __bf16* gsA  = XBp + (m0 + 16 * wv + (l >> 2)) * (size_t)KX + swcol;
    const __bf16* gsB0 = WBp + (n0 + 32 * wv + (l >> 2)) * (size_t)KX + swcol;
    const __bf16* gsB1 = gsB0 + (size_t)16 * KX;
    const int dA  = wv * 1024;                /* A rows 16wv..  (wave-uniform) */
    const int dB0 = 8192 + wv * 2048;
    const int dB1 = dB0 + 1024;

    /* fragment read: row R, logical k-slot fq -> phys fq ^ ((R>>1)&3) */
    const int fr = l & 15, fq = l >> 4;
    const int swz = (fq ^ ((fr >> 1) & 3)) << 4;
    const int aBase = (wm * 64 + fr) * 64 + swz;
    const int bBase = 8192 + (wn * 64 + fr) * 64 + swz;

    f32x4 acc[4][4] = {};

#define STAGE(STB)                                                            \
    {                                                                         \
        gload_lds16(gsA,  smem + (STB) + dA);                                 \
        gload_lds16(gsB0, smem + (STB) + dB0);                                \
        gload_lds16(gsB1, smem + (STB) + dB1);                                \
        gsA += 32; gsB0 += 32; gsB1 += 32;                                    \
    }

    /* prologue: chunks 0,1 -> slots 0,1 */
    STAGE(0); STAGE(SLOTSZ);

    int sb = 0, st = 2 * SLOTSZ;
    #pragma unroll 1
    for (int s = 0; s < NSUB - 2; ++s) {
        asm volatile("s_waitcnt vmcnt(3)" ::: "memory");
        __builtin_amdgcn_s_barrier();
        bf16x8 fa[4], fb[4];
        #pragma unroll
        for (int nf = 0; nf < 4; ++nf)
            fb[nf] = *(const bf16x8*)(smem + sb + bBase + nf * 1024);
        #pragma unroll
        for (int mf = 0; mf < 4; ++mf)
            fa[mf] = *(const bf16x8*)(smem + sb + aBase + mf * 1024);
        STAGE(st);
        __builtin_amdgcn_sched_barrier(0);
        __builtin_amdgcn_s_setprio(1);
        #pragma unroll
        for (int mf = 0; mf < 4; ++mf)
            #pragma unroll
            for (int nf = 0; nf < 4; ++nf)
                acc[mf][nf] = MFMA16(fa[mf], fb[nf], acc[mf][nf]);
        __builtin_amdgcn_s_setprio(0);
        sb += SLOTSZ; if (sb >= LDSZ) sb = 0;
        st += SLOTSZ; if (st >= LDSZ) st = 0;
    }
    /* tail: steps 64 (vmcnt 3), 65 (vmcnt 0), no staging */
    #pragma unroll 1
    for (int s = 0; s < 2; ++s) {
        if (s == 0) asm volatile("s_waitcnt vmcnt(3)" ::: "memory");
        else        asm volatile("s_waitcnt vmcnt(0)" ::: "memory");
        __builtin_amdgcn_s_barrier();
        bf16x8 fa[4], fb[4];
        #pragma unroll
        for (int nf = 0; nf < 4; ++nf)
            fb[nf] = *(const bf16x8*)(smem + sb + bBase + nf * 1024);
        #pragma unroll
        for (int mf = 0; mf < 4; ++mf)
            fa[mf] = *(const bf16x8*)(smem + sb + aBase + mf * 1024);
        __builtin_amdgcn_s_setprio(1);
        #pragma unroll
        for (int mf = 0; mf < 4; ++mf)
            #pragma unroll
            for (int nf = 0; nf < 4; ++nf)
                acc[mf][nf] = MFMA16(fa[mf], fb[nf], acc[mf][nf]);
        __builtin_amdgcn_s_setprio(0);
        sb += SLOTSZ; if (sb >= LDSZ) sb = 0;
    }
#undef STAGE

    /* epilogue: C = acc + bias */
    const int cr = (l >> 4) << 2;
    const int cc = l & 15;
    const size_t crow = m0 + wm * 64 + cr;
    const size_t ccol = n0 + wn * 64 + cc;
    #pragma unroll
    for (int nf = 0; nf < 4; ++nf) {
        const float bv = bias[ccol + nf * 16];
        #pragma unroll
        for (int mf = 0; mf < 4; ++mf) {
            float* cp = C + (crow + (size_t)mf * 16) * DOUT + ccol + nf * 16;
            #pragma unroll
            for (int i = 0; i < 4; ++i)
                cp[(size_t)i * DOUT] = acc[mf][nf][i] + bv;
        }
    }
}

extern "C" void kernel_launch(void* const* d_in, const int* in_sizes, int n_in,
                              void* d_out, int out_size, void* d_ws, size_t ws_size,
                              hipStream_t stream) {
    const float* x  = (const float*)d_in[0];
    const float* Wf = (const float*)d_in[1];
    const float* bf = (const float*)d_in[2];
    const float* Wr = (const float*)d_in[3];
    const float* br = (const float*)d_in[4];
    const float* A  = (const float*)d_in[5];
    const float* Bm = (const float*)d_in[6];

    float* out0 = (float*)d_out;
    float* wOut = out0 + (size_t)BT * DOUT;

    char* ws = (char*)d_ws;
    __bf16* XB   = (__bf16*)(ws + XB_OFF);
    __bf16* WB   = (__bf16*)(ws + WB_OFF);
    __bf16* ACAT = (__bf16*)(ws + ACAT_OFF);
    float*  HP   = (float*)(ws + HP_OFF);

    /* 1. weights -> bf16 layouts */
    mole_prep<<<4864, 256, 0, stream>>>(Wf, Bm, Wr, A, WB, ACAT);
    /* 2. fused: x->bf16 (+XB side-write) + [logit|h] partials vs ACAT */
    mole_hconv<<<dim3(64, 1, NSPLIT), 256, 0, stream>>>(x, ACAT, XB, HP);
    /* 3. softmax(+br) -> w out; g -> XB tail cols */
    mole_softmax_g<<<BT / 4, 256, 0, stream>>>(HP, br, wOut, XB);
    /* 4. out = [xb|g] @ [Wfb|Bcat]^T + bf  (128x256 tile, 2 blocks/CU) */
    mole_gemm128x256<<<512, 512, 0, stream>>>(XB, WB, out0, bf);
}

// Round 15
// 111.046 us; speedup vs baseline: 1.0079x; 1.0079x over previous
//
#include <hip/hip_runtime.h>
#include <hip/hip_bf16.h>

#define BT      8192
#define DIN     2048
#define DOUT    2048
#define NEXP    8
#define RANK    8
#define KX      2112         /* DIN + NEXP*RANK */
#define NSUB    66           /* KX / 32 */
#define NSPLIT  4            /* K-split for the h-GEMM */
#define HLD     72           /* HP leading dim: cols 0-7 logits, 8-71 h */
#define SCALING 1.0f         /* ALPHA / RANK = 8/8 */
#define SLOT    32768

typedef __bf16 bf16x8 __attribute__((ext_vector_type(8)));
typedef __bf16 bf16x4 __attribute__((ext_vector_type(4)));
typedef float  f32x4  __attribute__((ext_vector_type(4)));

/* ---- ws layout (bytes) ---- */
#define XB_OFF     0
#define XB_BYTES   (BT * KX * 2)
#define WB_OFF     (XB_OFF + XB_BYTES)
#define WB_BYTES   (DOUT * KX * 2)
#define ACAT_OFF   (WB_OFF + WB_BYTES)
#define ACAT_BYTES (128 * DIN * 2)
#define HP_OFF     (ACAT_OFF + ACAT_BYTES)
#define HP_BYTES   (NSPLIT * BT * HLD * 4)

__device__ __forceinline__ void gload_lds16(const void* g, void* l) {
    __builtin_amdgcn_global_load_lds(
        (__attribute__((address_space(1))) void*)(g),
        (__attribute__((address_space(3))) void*)(l),
        16, 0, 0);
}

#define MFMA16(a, b, c) __builtin_amdgcn_mfma_f32_16x16x32_bf16((a), (b), (c), 0, 0, 0)

/* ---------------- prep: weights -> bf16 staged layouts ---------------- */
__global__ __launch_bounds__(256) void mole_prep(
    const float* __restrict__ Wf, const float* __restrict__ Bm,
    const float* __restrict__ Wr, const float* __restrict__ A,
    __bf16* __restrict__ WB, __bf16* __restrict__ ACAT)
{
    const int i = blockIdx.x * 256 + threadIdx.x;
    const int R1 = DOUT * (DIN / 4);
    const int R2 = DOUT * 64;
    if (i < R1) {
        const int o = i >> 9, c4 = i & 511;
        float4 v = ((const float4*)Wf)[(size_t)o * 512 + c4];
        bf16x4 b; b[0] = (__bf16)v.x; b[1] = (__bf16)v.y; b[2] = (__bf16)v.z; b[3] = (__bf16)v.w;
        *(bf16x4*)&WB[(size_t)o * KX + (c4 << 2)] = b;
    } else if (i < R1 + R2) {
        const int j = i - R1;
        const int o = j >> 6, c = j & 63;
        const int e = c >> 3, r = c & 7;
        WB[(size_t)o * KX + DIN + c] = (__bf16)Bm[((size_t)e * DOUT + o) * RANK + r];
    } else {
        const int j = i - (R1 + R2);
        const int r = j >> 9, c4 = j & 511;
        float4 v;
        if (r < 8)        v = ((const float4*)Wr)[(size_t)r * 512 + c4];
        else if (r < 72)  v = ((const float4*)A)[(size_t)(r - 8) * 512 + c4];
        else              v = make_float4(0.f, 0.f, 0.f, 0.f);
        bf16x4 b; b[0] = (__bf16)v.x; b[1] = (__bf16)v.y; b[2] = (__bf16)v.z; b[3] = (__bf16)v.w;
        *(bf16x4*)&ACAT[(size_t)r * DIN + (c4 << 2)] = b;
    }
}

/* ==== fused h-GEMM: x(fp32)->bf16 convert + XB side-write + MFMA vs ACAT ==== */
__global__ __launch_bounds__(256) void mole_hconv(
    const float* __restrict__ x, const __bf16* __restrict__ ACAT,
    __bf16* __restrict__ XB, float* __restrict__ HP)
{
    __shared__ __align__(16) __bf16 Xs[128][32];
    __shared__ __align__(16) __bf16 Bs[128][32];

    const int tid = threadIdx.x;
    const int wv  = tid >> 6, ln = tid & 63;
    const int wr  = wv >> 1, wc = wv & 1;
    const size_t m0 = (size_t)blockIdx.x * 128;
    const int kStart = blockIdx.z * (DIN / NSPLIT);
    float* C = HP + (size_t)blockIdx.z * BT * HLD;

    const int xr = tid >> 3;
    const int xc = (tid & 7) << 2;
    const float* gx  = x  + (m0 + xr) * (size_t)DIN + kStart + xc;
    __bf16*      gxb = XB + (m0 + xr) * (size_t)KX  + kStart + xc;

    const int srow = (wv << 4) + (ln >> 2);
    const int scol = (ln & 3) << 3;
    const __bf16* gB0 = ACAT + srow * (size_t)DIN + kStart + scol;
    const __bf16* gB1 = gB0 + (size_t)64 * DIN;
    __bf16* lB0 = &Bs[(wv << 4)][0];
    __bf16* lB1 = &Bs[64 + (wv << 4)][0];

    f32x4 acc[4][4] = {};
    const int fr = ln & 15;
    const int fk = (ln >> 4) << 3;

    for (int ks = 0; ks < (DIN / NSPLIT) / 32; ++ks) {
        gload_lds16(gB0, lB0);
        gload_lds16(gB1, lB1);
        gB0 += 32; gB1 += 32;
        #pragma unroll
        for (int j = 0; j < 4; ++j) {
            float4 v = *(const float4*)(gx + (size_t)(32 * j) * DIN + 32 * ks);
            bf16x4 b; b[0] = (__bf16)v.x; b[1] = (__bf16)v.y;
            b[2] = (__bf16)v.z; b[3] = (__bf16)v.w;
            *(bf16x4*)&Xs[xr + 32 * j][xc] = b;
            *(bf16x4*)(gxb + (size_t)(32 * j) * KX + 32 * ks) = b;
        }
        __syncthreads();

        bf16x8 af[4], bfr[4];
        #pragma unroll
        for (int m = 0; m < 4; ++m)
            af[m] = *(const bf16x8*)&Xs[(wr << 6) + (m << 4) + fr][fk];
        #pragma unroll
        for (int n = 0; n < 4; ++n)
            bfr[n] = *(const bf16x8*)&Bs[(wc << 6) + (n << 4) + fr][fk];
        #pragma unroll
        for (int m = 0; m < 4; ++m)
            #pragma unroll
            for (int n = 0; n < 4; ++n)
                acc[m][n] = MFMA16(af[m], bfr[n], acc[m][n]);
        __syncthreads();
    }

    const int cr = (ln >> 4) << 2;
    const int cc = ln & 15;
    #pragma unroll
    for (int n = 0; n < 4; ++n) {
        const int col = (wc << 6) + (n << 4) + cc;
        if (col < HLD) {
            #pragma unroll
            for (int m = 0; m < 4; ++m) {
                const size_t row = m0 + (wr << 6) + (m << 4) + cr;
                #pragma unroll
                for (int r = 0; r < 4; ++r)
                    C[(row + r) * (size_t)HLD + col] = acc[m][n][r];
            }
        }
    }
}

/* --------- per-token: logits (HP cols 0-7 + br) -> softmax -> w; g -> XB --- */
__global__ __launch_bounds__(256) void mole_softmax_g(
    const float* __restrict__ HP, const float* __restrict__ br,
    float* __restrict__ wOut, __bf16* __restrict__ XB)
{
    const int t   = blockIdx.x * 4 + (threadIdx.x >> 6);
    const int tid = threadIdx.x & 63;
    float h = 0.0f;
    #pragma unroll
    for (int sp = 0; sp < NSPLIT; ++sp)
        h += HP[((size_t)sp * BT + t) * HLD + 8 + tid];

    float lg[NEXP];
    #pragma unroll
    for (int e = 0; e < NEXP; ++e) {
        lg[e] = br[e];
        #pragma unroll
        for (int sp = 0; sp < NSPLIT; ++sp)
            lg[e] += HP[((size_t)sp * BT + t) * HLD + e];
    }
    float mx = lg[0];
    #pragma unroll
    for (int e = 1; e < NEXP; ++e) mx = fmaxf(mx, lg[e]);
    float ex[NEXP], den = 0.0f;
    #pragma unroll
    for (int e = 0; e < NEXP; ++e) { ex[e] = expf(lg[e] - mx); den += ex[e]; }

    const float w_my = ex[tid >> 3] / den;
    XB[(size_t)t * KX + DIN + tid] = (__bf16)(SCALING * w_my * h);
    if (tid < NEXP) wOut[(size_t)t * NEXP + tid] = ex[tid] / den;
}

/* ==== main 256x256 GEMM: 4 FAT waves (128x128 out each), ring-4 BK=32 ====
   C[8192,2048] = XB * WB^T + bias. LDS-read BW is the measured binding
   resource (R14): read volume/step = #waves x (Mw+Nw) x 64B. 4 waves @
   128x128 -> 64 b128/step vs 8 waves @ 128x64 -> 96. Same FLOPs, 1.5x
   less LDS-read traffic. acc 8x8 f32x4 = 256 VGPR (+frags ~100, under
   the 450 no-spill line, m08). 1 wave/SIMD; latency hiding via counted-
   vmcnt DMA staging (waves not needed for loads in flight).
   LDS = 4 ring slots x 32 KB ([A 256x32 | B 256x32], 64 B/row; swizzle
   phys16B = k ^ ((row>>1)&3), 0-conflict verified). Per chunk per wave:
   8 gload_lds (A rows 64wv.. 4x, B rows 64wv.. 4x). Flight 3 chunks =
   24 loads; vmcnt(16) at step s completes exactly chunk s. WAR: stage
   (s+3)&3 overwrites slot s-1, read before step s-1's MFMAs which
   precede barrier s. Tail vmcnt 16/8/0. */
__global__ __launch_bounds__(256, 1) void mole_gemm256(
    const __bf16* __restrict__ XBp, const __bf16* __restrict__ WBp,
    float* __restrict__ C, const float* __restrict__ bias)
{
    __shared__ __align__(16) char smem[131072];

    const int tid = threadIdx.x;
    const int wv  = tid >> 6, l = tid & 63;
    const int wm  = wv >> 1, wn = wv & 1;
    const int bid = blockIdx.x;
    const int xcd = bid & 7, ib = bid >> 3;
    const int tm = xcd * 4 + (ib & 3), tn = ib >> 2;
    const size_t m0 = (size_t)tm * 256, n0 = (size_t)tn * 256;

    /* staging: wave wv covers A rows [64wv,64wv+64) and B rows likewise.
       lane l -> row +(l>>2), phys slot l&3, logical col ((l&3)^((l>>3)&3))*8 */
    const int swcol = ((l & 3) ^ ((l >> 3) & 3)) << 3;
    const __bf16* gsA = XBp + (m0 + 64 * wv + (l >> 2)) * (size_t)KX + swcol;
    const __bf16* gsB = WBp + (n0 + 64 * wv + (l >> 2)) * (size_t)KX + swcol;
    const int dA = wv * 4096;            /* wave-uniform LDS dests */
    const int dB = 16384 + wv * 4096;

    /* fragment read: row R, logical k-slot fq -> phys slot fq ^ ((R>>1)&3) */
    const int fr = l & 15, fq = l >> 4;
    const int swz = (fq ^ ((fr >> 1) & 3)) << 4;
    const int aByte = (wm * 128 + fr) * 64 + swz;
    const int bByte = 16384 + (wn * 128 + fr) * 64 + swz;

    f32x4 acc[8][8] = {};

#define STAGE(S)                                                              \
    {                                                                         \
        char* base = smem + ((S) & 3) * SLOT;                                 \
        const __bf16* gA_ = gsA + (size_t)(S) * 32;                           \
        const __bf16* gB_ = gsB + (size_t)(S) * 32;                           \
        _Pragma("unroll")                                                     \
        for (int j = 0; j < 4; ++j)                                           \
            gload_lds16(gA_ + (size_t)j * 16 * KX, base + dA + j * 1024);     \
        _Pragma("unroll")                                                     \
        for (int j = 0; j < 4; ++j)                                           \
            gload_lds16(gB_ + (size_t)j * 16 * KX, base + dB + j * 1024);     \
    }

#define STEP(S, VMN, DOSTAGE)                                                 \
    {                                                                         \
        asm volatile("s_waitcnt vmcnt(" #VMN ")" ::: "memory");               \
        __builtin_amdgcn_s_barrier();                                         \
        const char* slot = smem + ((S) & 3) * SLOT;                           \
        bf16x8 fa[8], fb[8];                                                  \
        _Pragma("unroll")                                                     \
        for (int nf = 0; nf < 8; ++nf)                                        \
            fb[nf] = *(const bf16x8*)(slot + bByte + nf * 1024);              \
        _Pragma("unroll")                                                     \
        for (int mf = 0; mf < 8; ++mf)                                        \
            fa[mf] = *(const bf16x8*)(slot + aByte + mf * 1024);              \
        if (DOSTAGE) STAGE((S) + 3);                                          \
        __builtin_amdgcn_sched_barrier(0);                                    \
        __builtin_amdgcn_s_setprio(1);                                        \
        _Pragma("unroll")                                                     \
        for (int mf = 0; mf < 8; ++mf)                                        \
            _Pragma("unroll")                                                 \
            for (int nf = 0; nf < 8; ++nf)                                    \
                acc[mf][nf] = MFMA16(fa[mf], fb[nf], acc[mf][nf]);            \
        __builtin_amdgcn_s_setprio(0);                                        \
    }

    /* prologue: stage chunks 0,1,2 (24 loads/wave) */
    STAGE(0); STAGE(1); STAGE(2);

    #pragma unroll 1
    for (int s = 0; s < NSUB - 3; ++s)
        STEP(s, 16, true);
    STEP(NSUB - 3, 16, false);
    STEP(NSUB - 2, 8,  false);
    STEP(NSUB - 1, 0,  false);
#undef STEP
#undef STAGE

    /* epilogue: C = acc + bias */
    const size_t crow = m0 + wm * 128 + fq * 4;
    const size_t ccol = n0 + wn * 128 + fr;
    #pragma unroll
    for (int nf = 0; nf < 8; ++nf) {
        const float bv = bias[ccol + nf * 16];
        #pragma unroll
        for (int mf = 0; mf < 8; ++mf) {
            float* cp = C + (crow + (size_t)mf * 16) * DOUT + ccol + nf * 16;
            #pragma unroll
            for (int i = 0; i < 4; ++i)
                cp[(size_t)i * DOUT] = acc[mf][nf][i] + bv;
        }
    }
}

extern "C" void kernel_launch(void* const* d_in, const int* in_sizes, int n_in,
                              void* d_out, int out_size, void* d_ws, size_t ws_size,
                              hipStream_t stream) {
    const float* x  = (const float*)d_in[0];
    const float* Wf = (const float*)d_in[1];
    const float* bf = (const float*)d_in[2];
    const float* Wr = (const float*)d_in[3];
    const float* br = (const float*)d_in[4];
    const float* A  = (const float*)d_in[5];
    const float* Bm = (const float*)d_in[6];

    float* out0 = (float*)d_out;
    float* wOut = out0 + (size_t)BT * DOUT;

    char* ws = (char*)d_ws;
    __bf16* XB   = (__bf16*)(ws + XB_OFF);
    __bf16* WB   = (__bf16*)(ws + WB_OFF);
    __bf16* ACAT = (__bf16*)(ws + ACAT_OFF);
    float*  HP   = (float*)(ws + HP_OFF);

    /* 1. weights -> bf16 layouts */
    mole_prep<<<4864, 256, 0, stream>>>(Wf, Bm, Wr, A, WB, ACAT);
    /* 2. fused: x->bf16 (+XB side-write) + [logit|h] partials vs ACAT */
    mole_hconv<<<dim3(64, 1, NSPLIT), 256, 0, stream>>>(x, ACAT, XB, HP);
    /* 3. softmax(+br) -> w out; g -> XB tail cols */
    mole_softmax_g<<<BT / 4, 256, 0, stream>>>(HP, br, wOut, XB);
    /* 4. out = [xb|g] @ [Wfb|Bcat]^T + bf  (4 fat waves, 128x128 each) */
    mole_gemm256<<<256, 256, 0, stream>>>(XB, WB, out0, bf);
}

// Round 16
// 101.058 us; speedup vs baseline: 1.1075x; 1.0988x over previous
//
#include <hip/hip_runtime.h>
#include <hip/hip_bf16.h>

#define BT      8192
#define DIN     2048
#define DOUT    2048
#define NEXP    8
#define RANK    8
#define KX      2112         /* DIN + NEXP*RANK */
#define NSPLIT  4            /* K-split for the h-GEMM */
#define HLD     72           /* HP leading dim: cols 0-7 logits, 8-71 h */
#define SCALING 1.0f         /* ALPHA / RANK = 8/8 */

typedef __bf16 bf16x8 __attribute__((ext_vector_type(8)));
typedef __bf16 bf16x4 __attribute__((ext_vector_type(4)));
typedef float  f32x4  __attribute__((ext_vector_type(4)));

/* ---- ws layout (bytes) ---- */
#define XB_OFF     0
#define XB_BYTES   (BT * KX * 2)
#define WB_OFF     (XB_OFF + XB_BYTES)
#define WB_BYTES   (DOUT * KX * 2)
#define ACAT_OFF   (WB_OFF + WB_BYTES)
#define ACAT_BYTES (128 * DIN * 2)
#define HP_OFF     (ACAT_OFF + ACAT_BYTES)
#define HP_BYTES   (NSPLIT * BT * HLD * 4)

__device__ __forceinline__ void gload_lds16(const void* g, void* l) {
    __builtin_amdgcn_global_load_lds(
        (__attribute__((address_space(1))) void*)(g),
        (__attribute__((address_space(3))) void*)(l),
        16, 0, 0);
}

#define MFMA16(a, b, c) __builtin_amdgcn_mfma_f32_16x16x32_bf16((a), (b), (c), 0, 0, 0)

/* ---------------- prep: weights -> bf16 staged layouts ---------------- */
__global__ __launch_bounds__(256) void mole_prep(
    const float* __restrict__ Wf, const float* __restrict__ Bm,
    const float* __restrict__ Wr, const float* __restrict__ A,
    __bf16* __restrict__ WB, __bf16* __restrict__ ACAT)
{
    const int i = blockIdx.x * 256 + threadIdx.x;
    const int R1 = DOUT * (DIN / 4);
    const int R2 = DOUT * 64;
    if (i < R1) {
        const int o = i >> 9, c4 = i & 511;
        float4 v = ((const float4*)Wf)[(size_t)o * 512 + c4];
        bf16x4 b; b[0] = (__bf16)v.x; b[1] = (__bf16)v.y; b[2] = (__bf16)v.z; b[3] = (__bf16)v.w;
        *(bf16x4*)&WB[(size_t)o * KX + (c4 << 2)] = b;
    } else if (i < R1 + R2) {
        const int j = i - R1;
        const int o = j >> 6, c = j & 63;
        const int e = c >> 3, r = c & 7;
        WB[(size_t)o * KX + DIN + c] = (__bf16)Bm[((size_t)e * DOUT + o) * RANK + r];
    } else {
        const int j = i - (R1 + R2);
        const int r = j >> 9, c4 = j & 511;
        float4 v;
        if (r < 8)        v = ((const float4*)Wr)[(size_t)r * 512 + c4];
        else if (r < 72)  v = ((const float4*)A)[(size_t)(r - 8) * 512 + c4];
        else              v = make_float4(0.f, 0.f, 0.f, 0.f);
        bf16x4 b; b[0] = (__bf16)v.x; b[1] = (__bf16)v.y; b[2] = (__bf16)v.z; b[3] = (__bf16)v.w;
        *(bf16x4*)&ACAT[(size_t)r * DIN + (c4 << 2)] = b;
    }
}

/* ==== fused h-GEMM: x(fp32)->bf16 convert + XB side-write + MFMA vs ACAT ==== */
__global__ __launch_bounds__(256) void mole_hconv(
    const float* __restrict__ x, const __bf16* __restrict__ ACAT,
    __bf16* __restrict__ XB, float* __restrict__ HP)
{
    __shared__ __align__(16) __bf16 Xs[128][32];
    __shared__ __align__(16) __bf16 Bs[128][32];

    const int tid = threadIdx.x;
    const int wv  = tid >> 6, ln = tid & 63;
    const int wr  = wv >> 1, wc = wv & 1;
    const size_t m0 = (size_t)blockIdx.x * 128;
    const int kStart = blockIdx.z * (DIN / NSPLIT);
    float* C = HP + (size_t)blockIdx.z * BT * HLD;

    const int xr = tid >> 3;
    const int xc = (tid & 7) << 2;
    const float* gx  = x  + (m0 + xr) * (size_t)DIN + kStart + xc;
    __bf16*      gxb = XB + (m0 + xr) * (size_t)KX  + kStart + xc;

    const int srow = (wv << 4) + (ln >> 2);
    const int scol = (ln & 3) << 3;
    const __bf16* gB0 = ACAT + srow * (size_t)DIN + kStart + scol;
    const __bf16* gB1 = gB0 + (size_t)64 * DIN;
    __bf16* lB0 = &Bs[(wv << 4)][0];
    __bf16* lB1 = &Bs[64 + (wv << 4)][0];

    f32x4 acc[4][4] = {};
    const int fr = ln & 15;
    const int fk = (ln >> 4) << 3;

    for (int ks = 0; ks < (DIN / NSPLIT) / 32; ++ks) {
        gload_lds16(gB0, lB0);
        gload_lds16(gB1, lB1);
        gB0 += 32; gB1 += 32;
        #pragma unroll
        for (int j = 0; j < 4; ++j) {
            float4 v = *(const float4*)(gx + (size_t)(32 * j) * DIN + 32 * ks);
            bf16x4 b; b[0] = (__bf16)v.x; b[1] = (__bf16)v.y;
            b[2] = (__bf16)v.z; b[3] = (__bf16)v.w;
            *(bf16x4*)&Xs[xr + 32 * j][xc] = b;
            *(bf16x4*)(gxb + (size_t)(32 * j) * KX + 32 * ks) = b;
        }
        __syncthreads();

        bf16x8 af[4], bfr[4];
        #pragma unroll
        for (int m = 0; m < 4; ++m)
            af[m] = *(const bf16x8*)&Xs[(wr << 6) + (m << 4) + fr][fk];
        #pragma unroll
        for (int n = 0; n < 4; ++n)
            bfr[n] = *(const bf16x8*)&Bs[(wc << 6) + (n << 4) + fr][fk];
        #pragma unroll
        for (int m = 0; m < 4; ++m)
            #pragma unroll
            for (int n = 0; n < 4; ++n)
                acc[m][n] = MFMA16(af[m], bfr[n], acc[m][n]);
        __syncthreads();
    }

    const int cr = (ln >> 4) << 2;
    const int cc = ln & 15;
    #pragma unroll
    for (int n = 0; n < 4; ++n) {
        const int col = (wc << 6) + (n << 4) + cc;
        if (col < HLD) {
            #pragma unroll
            for (int m = 0; m < 4; ++m) {
                const size_t row = m0 + (wr << 6) + (m << 4) + cr;
                #pragma unroll
                for (int r = 0; r < 4; ++r)
                    C[(row + r) * (size_t)HLD + col] = acc[m][n][r];
            }
        }
    }
}

/* --------- per-token: logits (HP cols 0-7 + br) -> softmax -> w; g -> XB --- */
__global__ __launch_bounds__(256) void mole_softmax_g(
    const float* __restrict__ HP, const float* __restrict__ br,
    float* __restrict__ wOut, __bf16* __restrict__ XB)
{
    const int t   = blockIdx.x * 4 + (threadIdx.x >> 6);
    const int tid = threadIdx.x & 63;
    float h = 0.0f;
    #pragma unroll
    for (int sp = 0; sp < NSPLIT; ++sp)
        h += HP[((size_t)sp * BT + t) * HLD + 8 + tid];

    float lg[NEXP];
    #pragma unroll
    for (int e = 0; e < NEXP; ++e) {
        lg[e] = br[e];
        #pragma unroll
        for (int sp = 0; sp < NSPLIT; ++sp)
            lg[e] += HP[((size_t)sp * BT + t) * HLD + e];
    }
    float mx = lg[0];
    #pragma unroll
    for (int e = 1; e < NEXP; ++e) mx = fmaxf(mx, lg[e]);
    float ex[NEXP], den = 0.0f;
    #pragma unroll
    for (int e = 0; e < NEXP; ++e) { ex[e] = expf(lg[e] - mx); den += ex[e]; }

    const float w_my = ex[tid >> 3] / den;
    XB[(size_t)t * KX + DIN + tid] = (__bf16)(SCALING * w_my * h);
    if (tid < NEXP) wOut[(size_t)t * NEXP + tid] = ex[tid] / den;
}

/* ========== main 256x256 GEMM: m201-style 8-phase, BK=64 dbuf ==========
   Best-measured-total configuration (R11: 100.9 us). 8 waves (2M x 4N),
   per-wave 128x64. LDS 128KB = 2 buf x [A 256x64 | B 256x64] (128B rows,
   8x16B slots; phys slot = logical ^ (row&7), 0-conflict verified;
   staged via pre-swizzled global source, linear LDS dest). Per iteration
   2 K-tiles x 4 phases x 16 MFMA; vmcnt(6) only at phases 4/8 before the
   closing barrier (publish); lgkm(8) throttle on 12-read phases. */
__global__ __launch_bounds__(512, 1) void mole_gemm256(
    const __bf16* __restrict__ XBp, const __bf16* __restrict__ WBp,
    float* __restrict__ C, const float* __restrict__ bias)
{
    __shared__ __align__(16) char smem[131072];

    const int tid = threadIdx.x;
    const int wv  = tid >> 6, l = tid & 63;
    const int wm  = wv >> 2, wn = wv & 3;
    const int bid = blockIdx.x;
    const int xcd = bid & 7, ib = bid >> 3;
    const int tm = xcd * 4 + (ib & 3), tn = ib >> 2;
    const size_t m0 = (size_t)tm * 256, n0 = (size_t)tn * 256;

    const __bf16* gA = XBp + (m0 + (l >> 3)) * KX + (((l & 7) ^ (l >> 3)) << 3);
    const __bf16* gB = WBp + (n0 + (l >> 3)) * KX + (((l & 7) ^ (l >> 3)) << 3);
    const int wv8 = wv * 8;
    const int rbB = ((wv & 3) * 8) + ((wv >> 2) * 64);

    const int fr = l & 15, fq = l >> 4;
    const int sw0 = ((fq)     ^ (fr & 7)) << 4;
    const int sw1 = ((4 + fq) ^ (fr & 7)) << 4;
    const int aOff = (wm * 128 + fr) * 128;
    const int bOff = 32768 + (wn * 64 + fr) * 128;

    f32x4 acc[8][4] = {};
    bf16x8 fa[4][2], fa2[4][2], fb[2][2], fb2[2][2];

#define GLA(RB, T, BUF)                                                       \
    gload_lds16(gA + (size_t)((RB) + wv8) * KX + (size_t)(T) * 64,            \
                smem + (BUF) * 65536 + ((RB) + wv8) * 128)
#define GLB(RB, T, BUF)                                                       \
    gload_lds16(gB + (size_t)((RB) + rbB) * KX + (size_t)(T) * 64,            \
                smem + (BUF) * 65536 + 32768 + ((RB) + rbB) * 128)
#define ST_AQ1(T, BUF) { GLA(0, T, BUF);  GLA(128, T, BUF); }
#define ST_AQ2(T, BUF) { GLA(64, T, BUF); GLA(192, T, BUF); }
#define ST_BH1(T, BUF) { GLB(0, T, BUF);  GLB(128, T, BUF); }
#define ST_BH2(T, BUF) { GLB(32, T, BUF); GLB(160, T, BUF); }

#define RD_FA(ARR, B0, PB)                                                    \
    _Pragma("unroll")                                                         \
    for (int mf = 0; mf < 4; ++mf) {                                          \
        const char* a_ = smem + (PB) * 65536 + aOff + ((B0) + mf) * 2048;     \
        ARR[mf][0] = *(const bf16x8*)(a_ + sw0);                              \
        ARR[mf][1] = *(const bf16x8*)(a_ + sw1);                              \
    }
#define RD_FB(ARR, B0, PB)                                                    \
    _Pragma("unroll")                                                         \
    for (int nf = 0; nf < 2; ++nf) {                                          \
        const char* b_ = smem + (PB) * 65536 + bOff + ((B0) + nf) * 2048;     \
        ARR[nf][0] = *(const bf16x8*)(b_ + sw0);                              \
        ARR[nf][1] = *(const bf16x8*)(b_ + sw1);                              \
    }
#define MM(FA, FB, MB, NB)                                                    \
    __builtin_amdgcn_s_setprio(1);                                            \
    _Pragma("unroll")                                                         \
    for (int kk = 0; kk < 2; ++kk)                                            \
        _Pragma("unroll")                                                     \
        for (int mf = 0; mf < 4; ++mf)                                        \
            _Pragma("unroll")                                                 \
            for (int nf = 0; nf < 2; ++nf)                                    \
                acc[(MB) + mf][(NB) + nf] =                                   \
                    MFMA16(FA[mf][kk], FB[nf][kk], acc[(MB) + mf][(NB) + nf]);\
    __builtin_amdgcn_s_setprio(0);
#define MIDBAR { __builtin_amdgcn_s_barrier();                                \
                 asm volatile("s_waitcnt lgkmcnt(0)" ::: "memory");           \
                 __builtin_amdgcn_sched_barrier(0); }
#define ENDBAR __builtin_amdgcn_s_barrier();
#define LG8    asm volatile("s_waitcnt lgkmcnt(8)" ::: "memory");
#define VMC(N) asm volatile("s_waitcnt vmcnt(" #N ")" ::: "memory");

    /* prologue: tile0 full + tile1 {Aq1,Bh1,Bh2} = 14 loads; drain tile0 */
    ST_AQ1(0, 0); ST_BH1(0, 0); ST_BH2(0, 0); ST_AQ2(0, 0);
    ST_AQ1(1, 1); ST_BH1(1, 1); ST_BH2(1, 1);
    VMC(6); ENDBAR;

    #pragma unroll 1
    for (int i = 0; i < 15; ++i) {
        const int t = 2 * i;
        RD_FA(fa, 0, 0); RD_FB(fb, 0, 0);
        ST_AQ2(t + 1, 1);
        LG8; MIDBAR; MM(fa, fb, 0, 0); ENDBAR;
        RD_FB(fb2, 2, 0);
        ST_AQ1(t + 2, 0);
        MIDBAR; MM(fa, fb2, 0, 2); ENDBAR;
        RD_FA(fa2, 4, 0);
        ST_BH1(t + 2, 0);
        MIDBAR; MM(fa2, fb, 4, 0); ENDBAR;
        ST_BH2(t + 2, 0);
        MIDBAR; MM(fa2, fb2, 4, 2); VMC(6); ENDBAR;
        RD_FA(fa, 0, 1); RD_FB(fb, 0, 1);
        ST_AQ2(t + 2, 0);
        LG8; MIDBAR; MM(fa, fb, 0, 0); ENDBAR;
        RD_FB(fb2, 2, 1);
        ST_AQ1(t + 3, 1);
        MIDBAR; MM(fa, fb2, 0, 2); ENDBAR;
        RD_FA(fa2, 4, 1);
        ST_BH1(t + 3, 1);
        MIDBAR; MM(fa2, fb, 4, 0); ENDBAR;
        ST_BH2(t + 3, 1);
        MIDBAR; MM(fa2, fb2, 4, 2); VMC(6); ENDBAR;
    }
    /* iter 15: tiles 30,31; stages only tile 32 -> buf0 */
    {
        RD_FA(fa, 0, 0); RD_FB(fb, 0, 0);
        ST_AQ2(31, 1);
        LG8; MIDBAR; MM(fa, fb, 0, 0); ENDBAR;
        RD_FB(fb2, 2, 0);
        ST_AQ1(32, 0);
        MIDBAR; MM(fa, fb2, 0, 2); ENDBAR;
        RD_FA(fa2, 4, 0);
        ST_BH1(32, 0);
        MIDBAR; MM(fa2, fb, 4, 0); ENDBAR;
        ST_BH2(32, 0);
        MIDBAR; MM(fa2, fb2, 4, 2); VMC(6); ENDBAR;
        RD_FA(fa, 0, 1); RD_FB(fb, 0, 1);
        ST_AQ2(32, 0);
        LG8; MIDBAR; MM(fa, fb, 0, 0); ENDBAR;
        RD_FB(fb2, 2, 1);
        MIDBAR; MM(fa, fb2, 0, 2); ENDBAR;
        RD_FA(fa2, 4, 1);
        MIDBAR; MM(fa2, fb, 4, 0); ENDBAR;
        MIDBAR; MM(fa2, fb2, 4, 2); VMC(4); ENDBAR;
    }
    /* tail: tile 32 on buf0; drain 2 -> 0 */
    {
        RD_FA(fa, 0, 0); RD_FB(fb, 0, 0);
        LG8; MIDBAR; MM(fa, fb, 0, 0); VMC(2); ENDBAR;
        RD_FB(fb2, 2, 0);
        MIDBAR; MM(fa, fb2, 0, 2); VMC(0); ENDBAR;
        RD_FA(fa2, 4, 0);
        MIDBAR; MM(fa2, fb, 4, 0); ENDBAR;
        MM(fa2, fb2, 4, 2);
    }
#undef GLA
#undef GLB
#undef ST_AQ1
#undef ST_AQ2
#undef ST_BH1
#undef ST_BH2
#undef RD_FA
#undef RD_FB
#undef MM
#undef MIDBAR
#undef ENDBAR
#undef LG8
#undef VMC

    /* epilogue: C = acc + bias */
    const size_t crow = m0 + wm * 128 + fq * 4;
    const size_t ccol = n0 + wn * 64 + fr;
    #pragma unroll
    for (int nf = 0; nf < 4; ++nf) {
        const float bv = bias[ccol + nf * 16];
        #pragma unroll
        for (int mf = 0; mf < 8; ++mf) {
            float* cp = C + (crow + (size_t)mf * 16) * DOUT + ccol + nf * 16;
            #pragma unroll
            for (int i = 0; i < 4; ++i)
                cp[(size_t)i * DOUT] = acc[mf][nf][i] + bv;
        }
    }
}

extern "C" void kernel_launch(void* const* d_in, const int* in_sizes, int n_in,
                              void* d_out, int out_size, void* d_ws, size_t ws_size,
                              hipStream_t stream) {
    const float* x  = (const float*)d_in[0];
    const float* Wf = (const float*)d_in[1];
    const float* bf = (const float*)d_in[2];
    const float* Wr = (const float*)d_in[3];
    const float* br = (const float*)d_in[4];
    const float* A  = (const float*)d_in[5];
    const float* Bm = (const float*)d_in[6];

    float* out0 = (float*)d_out;
    float* wOut = out0 + (size_t)BT * DOUT;

    char* ws = (char*)d_ws;
    __bf16* XB   = (__bf16*)(ws + XB_OFF);
    __bf16* WB   = (__bf16*)(ws + WB_OFF);
    __bf16* ACAT = (__bf16*)(ws + ACAT_OFF);
    float*  HP   = (float*)(ws + HP_OFF);

    /* 1. weights -> bf16 layouts */
    mole_prep<<<4864, 256, 0, stream>>>(Wf, Bm, Wr, A, WB, ACAT);
    /* 2. fused: x->bf16 (+XB side-write) + [logit|h] partials vs ACAT */
    mole_hconv<<<dim3(64, 1, NSPLIT), 256, 0, stream>>>(x, ACAT, XB, HP);
    /* 3. softmax(+br) -> w out; g -> XB tail cols */
    mole_softmax_g<<<BT / 4, 256, 0, stream>>>(HP, br, wOut, XB);
    /* 4. out = [xb|g] @ [Wfb|Bcat]^T + bf  (m201 8-phase) */
    mole_gemm256<<<256, 512, 0, stream>>>(XB, WB, out0, bf);
}